// Round 3
// baseline (74.455 us; speedup 1.0000x reference)
//
#include <hip/hip_runtime.h>

// Problem constants (from reference)
constexpr int Bn    = 262144;
constexpr int NNUM  = 64;
constexpr int FCAT  = 32;
constexpr int NCAT  = 8;
constexpr int NFEAT = NNUM + FCAT * NCAT;  // 320
constexpr int NPHEN = NNUM + FCAT;         // 96

// 2 * log2(e): prepped weights Wp = TWO_LOG2E * W, so that
// exp2(Wp·x) == exp(2·W·x), feeding v_exp_f32 directly.
constexpr float TWO_LOG2E = 2.8853900817779268f;

__global__ __launch_bounds__(256) void prep_kernel(
    const float* __restrict__ W, float* __restrict__ Wp)
{
    int i = blockIdx.x * 256 + threadIdx.x;
    if (i < 2 * NFEAT) Wp[i] = TWO_LOG2E * W[i];
}

// a = 2*log2e*(w·x)  ->  tanh(w·x) = 1 - 2/(exp2(a)+1)
// exp2(+inf)->inf -> rcp->0 -> +1 ; exp2(-inf)->0 -> rcp(1)=1 -> -1 (saturates)
__device__ __forceinline__ float tanh_e2(float a) {
    float e = __builtin_amdgcn_exp2f(a);
    float r = __builtin_amdgcn_rcpf(e + 1.0f);
    return fmaf(-2.0f, r, 1.0f);
}

__global__ __launch_bounds__(256) void model_kernel(
    const float* __restrict__ num_x,   // (B, 64)
    const float* __restrict__ cat_x,   // (32, B, 8)
    const float* __restrict__ Wp,      // (2, 320) pre-scaled by 2*log2e
    const float* __restrict__ M,       // (2, 96)
    float* __restrict__ out)           // (2, B)
{
    const int b = blockIdx.x * 256 + threadIdx.x;

    float f0 = 0.0f, f1 = 0.0f;

    // ---- numerical features: 16 x float4 per-thread row; all weight/M reads
    //      are compile-time-constant uniform indices -> s_load (scalar cache),
    //      no LDS pipe involvement.
    const float4* nx = reinterpret_cast<const float4*>(num_x + (size_t)b * NNUM);
    #pragma unroll
    for (int i = 0; i < NNUM / 4; ++i) {
        float4 v = nx[i];
        const float* vp = reinterpret_cast<const float*>(&v);
        #pragma unroll
        for (int j = 0; j < 4; ++j) {
            const int k = i * 4 + j;
            float x = vp[j];
            f0 = fmaf(M[k],         tanh_e2(Wp[k] * x),         f0);
            f1 = fmaf(M[NPHEN + k], tanh_e2(Wp[NFEAT + k] * x), f1);
        }
    }

    // ---- categorical features: fully coalesced per-lane float4 pairs;
    //      weights again scalar-register operands.
    #pragma unroll
    for (int f = 0; f < FCAT; ++f) {
        const float4* cx = reinterpret_cast<const float4*>(
            cat_x + (size_t)f * (size_t)Bn * NCAT + (size_t)b * NCAT);
        float4 v0 = cx[0];
        float4 v1 = cx[1];
        const float* p0 = reinterpret_cast<const float*>(&v0);
        const float* p1 = reinterpret_cast<const float*>(&v1);
        float d0 = 0.0f, d1 = 0.0f;   // accumulates 2*log2e * dot
        #pragma unroll
        for (int n = 0; n < 4; ++n) {
            d0 = fmaf(Wp[NNUM + f * NCAT + n],         p0[n], d0);
            d1 = fmaf(Wp[NFEAT + NNUM + f * NCAT + n], p0[n], d1);
        }
        #pragma unroll
        for (int n = 0; n < 4; ++n) {
            d0 = fmaf(Wp[NNUM + f * NCAT + 4 + n],         p1[n], d0);
            d1 = fmaf(Wp[NFEAT + NNUM + f * NCAT + 4 + n], p1[n], d1);
        }
        f0 = fmaf(M[NNUM + f],         tanh_e2(d0), f0);
        f1 = fmaf(M[NPHEN + NNUM + f], tanh_e2(d1), f1);
    }

    // ---- stable 2-class softmax: o0 = 1/(1+exp(f1-f0)) ----
    float e10 = __expf(f1 - f0);
    float o0  = __builtin_amdgcn_rcpf(1.0f + e10);
    out[b]              = o0;
    out[(size_t)Bn + b] = 1.0f - o0;
}

extern "C" void kernel_launch(void* const* d_in, const int* in_sizes, int n_in,
                              void* d_out, int out_size, void* d_ws, size_t ws_size,
                              hipStream_t stream) {
    const float* num_x = (const float*)d_in[0];
    const float* cat_x = (const float*)d_in[1];
    const float* W     = (const float*)d_in[2];
    const float* M     = (const float*)d_in[3];
    float* out = (float*)d_out;
    float* Wp  = (float*)d_ws;   // 640 floats of scratch

    hipLaunchKernelGGL(prep_kernel, dim3(3), dim3(256), 0, stream, W, Wp);
    hipLaunchKernelGGL(model_kernel, dim3(Bn / 256), dim3(256), 0, stream,
                       num_x, cat_x, Wp, M, out);
}

// Round 4
// 68.807 us; speedup vs baseline: 1.0821x; 1.0821x over previous
//
#include <hip/hip_runtime.h>

// Problem constants (from reference)
constexpr int Bn    = 262144;
constexpr int NNUM  = 64;
constexpr int FCAT  = 32;
constexpr int NCAT  = 8;
constexpr int NFEAT = NNUM + FCAT * NCAT;  // 320
constexpr int NPHEN = NNUM + FCAT;         // 96

// tanh(x) given a = 2x:  tanh(x) = 1 - 2/(exp(2x)+1)
__device__ __forceinline__ float tanh_from_2x(float a) {
    float e = __expf(a);
    float r = __builtin_amdgcn_rcpf(e + 1.0f);
    return fmaf(-2.0f, r, 1.0f);
}

__global__ __launch_bounds__(256) void model_kernel(
    const float* __restrict__ num_x,   // (B, 64)
    const float* __restrict__ cat_x,   // (32, B, 8)
    const float* __restrict__ W,       // (2, 320)
    const float* __restrict__ M,       // (2, 96)
    float* __restrict__ out)           // (2, B)
{
    // Weights in LDS (uniform-address broadcast reads, conflict-free).
    // sW2 = 2*W so dot products feed exp(2x) directly.
    __shared__ float sW2[2 * NFEAT];
    __shared__ float sM[2 * NPHEN];
    const int tid = threadIdx.x;
    for (int i = tid; i < 2 * NFEAT; i += 256) sW2[i] = 2.0f * W[i];
    for (int i = tid; i < 2 * NPHEN; i += 256) sM[i] = M[i];
    __syncthreads();

    // Two ADJACENT samples per thread: weight broadcasts amortized 2x,
    // cat reads become 64B-contiguous per lane, stores become float2.
    const int b = blockIdx.x * 512 + tid * 2;   // samples b, b+1

    float f0a = 0.0f, f1a = 0.0f;   // sample b
    float f0b = 0.0f, f1b = 0.0f;   // sample b+1

    // ---- numerical features: 2 rows x 16 float4 ----
    const float4* nxa = reinterpret_cast<const float4*>(num_x + (size_t)b * NNUM);
    const float4* nxb = nxa + NNUM / 4;
    #pragma unroll
    for (int i = 0; i < NNUM / 4; ++i) {
        float4 va = nxa[i];
        float4 vb = nxb[i];
        const float* pa = reinterpret_cast<const float*>(&va);
        const float* pb = reinterpret_cast<const float*>(&vb);
        #pragma unroll
        for (int j = 0; j < 4; ++j) {
            const int k = i * 4 + j;
            const float w0 = sW2[k],        w1 = sW2[NFEAT + k];
            const float m0 = sM[k],         m1 = sM[NPHEN + k];
            f0a = fmaf(m0, tanh_from_2x(w0 * pa[j]), f0a);
            f1a = fmaf(m1, tanh_from_2x(w1 * pa[j]), f1a);
            f0b = fmaf(m0, tanh_from_2x(w0 * pb[j]), f0b);
            f1b = fmaf(m1, tanh_from_2x(w1 * pb[j]), f1b);
        }
    }

    // ---- categorical features: per f, 64B contiguous per lane (4 x float4) ----
    #pragma unroll 4
    for (int f = 0; f < FCAT; ++f) {
        const float4* cx = reinterpret_cast<const float4*>(
            cat_x + (size_t)f * (size_t)Bn * NCAT + (size_t)b * NCAT);
        float4 va0 = cx[0];   // sample b,   n=0..3
        float4 va1 = cx[1];   // sample b,   n=4..7
        float4 vb0 = cx[2];   // sample b+1, n=0..3
        float4 vb1 = cx[3];   // sample b+1, n=4..7
        const float* a0 = reinterpret_cast<const float*>(&va0);
        const float* a1 = reinterpret_cast<const float*>(&va1);
        const float* b0p = reinterpret_cast<const float*>(&vb0);
        const float* b1p = reinterpret_cast<const float*>(&vb1);
        const float* w0 = &sW2[NNUM + f * NCAT];           // 2*W_cat[0][f][:]
        const float* w1 = &sW2[NFEAT + NNUM + f * NCAT];   // 2*W_cat[1][f][:]
        float d0a = 0.0f, d1a = 0.0f, d0b = 0.0f, d1b = 0.0f;  // 2*dot
        #pragma unroll
        for (int n = 0; n < 4; ++n) {
            const float wa0 = w0[n], wa1 = w1[n];
            d0a = fmaf(wa0, a0[n], d0a);
            d1a = fmaf(wa1, a0[n], d1a);
            d0b = fmaf(wa0, b0p[n], d0b);
            d1b = fmaf(wa1, b0p[n], d1b);
        }
        #pragma unroll
        for (int n = 0; n < 4; ++n) {
            const float wa0 = w0[4 + n], wa1 = w1[4 + n];
            d0a = fmaf(wa0, a1[n], d0a);
            d1a = fmaf(wa1, a1[n], d1a);
            d0b = fmaf(wa0, b1p[n], d0b);
            d1b = fmaf(wa1, b1p[n], d1b);
        }
        const float m0 = sM[NNUM + f], m1 = sM[NPHEN + NNUM + f];
        f0a = fmaf(m0, tanh_from_2x(d0a), f0a);
        f1a = fmaf(m1, tanh_from_2x(d1a), f1a);
        f0b = fmaf(m0, tanh_from_2x(d0b), f0b);
        f1b = fmaf(m1, tanh_from_2x(d1b), f1b);
    }

    // ---- stable 2-class softmax, float2 stores ----
    float ea = __expf(f1a - f0a);
    float eb = __expf(f1b - f0b);
    float oa = __builtin_amdgcn_rcpf(1.0f + ea);
    float ob = __builtin_amdgcn_rcpf(1.0f + eb);
    float2 r0 = make_float2(oa, ob);
    float2 r1 = make_float2(1.0f - oa, 1.0f - ob);
    *reinterpret_cast<float2*>(out + b)              = r0;
    *reinterpret_cast<float2*>(out + (size_t)Bn + b) = r1;
}

extern "C" void kernel_launch(void* const* d_in, const int* in_sizes, int n_in,
                              void* d_out, int out_size, void* d_ws, size_t ws_size,
                              hipStream_t stream) {
    const float* num_x = (const float*)d_in[0];
    const float* cat_x = (const float*)d_in[1];
    const float* W     = (const float*)d_in[2];
    const float* M     = (const float*)d_in[3];
    float* out = (float*)d_out;

    dim3 grid(Bn / 512), block(256);
    hipLaunchKernelGGL(model_kernel, grid, block, 0, stream,
                       num_x, cat_x, W, M, out);
}